// Round 6
// baseline (320.481 us; speedup 1.0000x reference)
//
#include <hip/hip_runtime.h>
#include <hip/hip_bf16.h>

// y[b,i] = sum_j x[b,j] * r[(j-i) mod N] + bias[i]
// xb = bf16(x), Bt[i][k] = bf16(r[(k-i)&mask]) in ws.
// GEMM: 256x256 tile, BK=32, ring-4 K-slots, lookahead-3 staging,
//       register-prefetch pipeline (frags read one tile ahead),
//       counted vmcnt(4), ONE barrier per K-tile.

typedef __attribute__((ext_vector_type(8))) short bf16x8;
typedef __attribute__((ext_vector_type(4))) float f32x4;
typedef __attribute__((ext_vector_type(8))) unsigned short us8;
typedef __attribute__((ext_vector_type(4))) unsigned short us4;

__device__ __forceinline__ unsigned short f2bf(float f) {
  union { __hip_bfloat16 h; unsigned short u; } v;
  v.h = __float2bfloat16(f);
  return v.u;
}

__device__ __forceinline__ void gload_lds16(const void* g, void* l) {
  __builtin_amdgcn_global_load_lds(
      (const __attribute__((address_space(1))) void*)g,
      (__attribute__((address_space(3))) void*)l, 16, 0, 0);
}

#define SBAR() __builtin_amdgcn_s_barrier()
#define VM0() asm volatile("s_waitcnt vmcnt(0)" ::: "memory")
#define VM4() asm volatile("s_waitcnt vmcnt(4)" ::: "memory")

// ---------------- converters ----------------

__global__ __launch_bounds__(256) void conv_x_kernel(
    const float* __restrict__ x, unsigned short* __restrict__ xb,
    size_t total8) {
  size_t i = (size_t)blockIdx.x * blockDim.x + threadIdx.x;
  const size_t stride = (size_t)gridDim.x * blockDim.x;
  for (; i < total8; i += stride) {
    const float4 v0 = ((const float4*)x)[2 * i];
    const float4 v1 = ((const float4*)x)[2 * i + 1];
    us8 o;
    o[0] = f2bf(v0.x); o[1] = f2bf(v0.y); o[2] = f2bf(v0.z); o[3] = f2bf(v0.w);
    o[4] = f2bf(v1.x); o[5] = f2bf(v1.y); o[6] = f2bf(v1.z); o[7] = f2bf(v1.w);
    ((us8*)xb)[i] = o;
  }
}

__global__ __launch_bounds__(256) void build_bt_kernel(
    const float* __restrict__ r, unsigned short* __restrict__ bt, int n,
    int logn) {
  const int mask = n - 1;
  const size_t total8 = ((size_t)n * n) >> 3;
  size_t i = (size_t)blockIdx.x * blockDim.x + threadIdx.x;
  const size_t stride = (size_t)gridDim.x * blockDim.x;
  for (; i < total8; i += stride) {
    const size_t e0 = i << 3;
    const int row = (int)(e0 >> logn);
    const int k0 = (int)(e0 & (size_t)mask);
    const int base = k0 - row;
    us8 o;
#pragma unroll
    for (int t = 0; t < 8; ++t) o[t] = f2bf(r[(base + t) & mask]);
    ((us8*)bt)[i] = o;
  }
}

// ---------------- 256x256 GEMM, BK=32, ring-4, reg-prefetch ----------------
// 8 waves (2M x 4N); per-wave C = 128x64 = acc[8][4] 16x16 frags.
// LDS: 4 K-slots x (A 256x32 + B 256x32) bf16 = 128 KiB.
// Slot layout: [row][4 chunks of 8 elems], phys_chunk = logical ^ ((row>>1)&3).
// Pipeline (body t):
//   qA <- ds_read tile t A(mi4-7)            [slot t&3]
//   MFMA half1: acc[0-3][*] += pA x pB       [regs prefetched in body t-1]
//   pA' <- ds_read tile t+1 A(mi0-3)         [slot (t+1)&3]
//   MFMA half2: acc[4-7][*] += qA x pB
//   pB' <- ds_read tile t+1 B                [slot (t+1)&3]
//   gload_lds tile t+3 -> slot (t+3)&3
//   VM4 (tile t+2 landed; own 4 newest in flight); SBAR
// Safety: slot written in body t is (t+3)&3 == (t-1)&3, whose last ds_reads
// (body t-1's qA or prefetch) were lgkm-consumed by MFMAs before the t-1-end
// barrier; writes issue after that barrier. Prefetch of slot (t+1)&3 in body
// t reads data guaranteed landed by the end-of-body-(t-1) VM4 and made
// visible by its barrier.

#define ASLOT 8192  // elems per slot (256*32)

__global__ __launch_bounds__(512, 2) void circ_gemm6(
    const unsigned short* __restrict__ A, const unsigned short* __restrict__ B,
    const float* __restrict__ bias, float* __restrict__ y, int n, int nbn) {
  __shared__ unsigned short As[4 * ASLOT];
  __shared__ unsigned short Bs[4 * ASLOT];

  // XCD-aware swizzle (nwg % 8 == 0: 512 blocks)
  const int nwg = gridDim.x;
  const int cpx = nwg >> 3;
  const int b0 = blockIdx.x;
  const int wg = (b0 & 7) * cpx + (b0 >> 3);
  const int bn0 = (wg % nbn) * 256;
  const int bm0 = (wg / nbn) * 256;

  const int tid = threadIdx.x;
  const int wid = tid >> 6;
  const int lane = tid & 63;
  const int wm = wid >> 2;  // 0..1
  const int wn = wid & 3;   // 0..3
  const int lr = lane & 15;
  const int g = lane >> 4;  // 0..3 (logical k-chunk)

  // ---- staging addressing ----
  const int lchunk = (lane & 3) ^ ((lane >> 3) & 3);
  unsigned aoff[2], boff[2];
  int ldso[2];
#pragma unroll
  for (int j = 0; j < 2; ++j) {
    const int instrow = (wid * 2 + j) * 16;
    aoff[j] = (unsigned)(bm0 + instrow + (lane >> 2)) * (unsigned)n + lchunk * 8;
    boff[j] = (unsigned)(bn0 + instrow + (lane >> 2)) * (unsigned)n + lchunk * 8;
    ldso[j] = instrow * 32;  // elems within slot
  }

  f32x4 acc[8][4];
#pragma unroll
  for (int i = 0; i < 8; ++i)
#pragma unroll
    for (int j = 0; j < 4; ++j) acc[i][j] = (f32x4){0.f, 0.f, 0.f, 0.f};

  const int aRow = wm * 128 + lr;               // + mi*16
  const int bRow = wn * 64 + lr;                // + ni*16
  const int csw = (g ^ ((lr >> 1) & 3)) << 3;   // swizzled chunk elem offset

  const int nt = n >> 5;  // K-tiles of 32

  // ---- prologue: stage tiles 0,1,2 -> slots 0,1,2 ----
#pragma unroll
  for (int j = 0; j < 2; ++j) gload_lds16(A + aoff[j], As + ldso[j]);
#pragma unroll
  for (int j = 0; j < 2; ++j) gload_lds16(B + boff[j], Bs + ldso[j]);
#pragma unroll
  for (int j = 0; j < 2; ++j) gload_lds16(A + aoff[j] + 32, As + ASLOT + ldso[j]);
#pragma unroll
  for (int j = 0; j < 2; ++j) gload_lds16(B + boff[j] + 32, Bs + ASLOT + ldso[j]);
#pragma unroll
  for (int j = 0; j < 2; ++j) gload_lds16(A + aoff[j] + 64, As + 2 * ASLOT + ldso[j]);
#pragma unroll
  for (int j = 0; j < 2; ++j) gload_lds16(B + boff[j] + 64, Bs + 2 * ASLOT + ldso[j]);
  VM4();  // tiles 0,1 landed; tile 2 may be in flight
  SBAR();

  // prefetch tile 0 half1 frags into registers
  bf16x8 pA[4], pB[4];
#pragma unroll
  for (int mi = 0; mi < 4; ++mi)
    pA[mi] = *(const bf16x8*)&As[(aRow + mi * 16) * 32 + csw];
#pragma unroll
  for (int ni = 0; ni < 4; ++ni)
    pB[ni] = *(const bf16x8*)&Bs[(bRow + ni * 16) * 32 + csw];

  for (int t = 0; t < nt; ++t) {
    const int rslot = (t & 3) * ASLOT;
    const int nslot = ((t + 1) & 3) * ASLOT;
    const int wslot = ((t + 3) & 3) * ASLOT;
    const unsigned kof = (unsigned)(t + 3) << 5;
    const bool pf = (t + 3) < nt;
    const bool rd = (t + 1) < nt;

    // half2 A-frags of tile t (issue early: LDS works during half1 MFMA)
    bf16x8 qA[4];
#pragma unroll
    for (int mi = 0; mi < 4; ++mi)
      qA[mi] = *(const bf16x8*)&As[rslot + (aRow + 64 + mi * 16) * 32 + csw];

    // half1 MFMA from prefetched regs (no LDS dependency)
    __builtin_amdgcn_s_setprio(1);
#pragma unroll
    for (int mi = 0; mi < 4; ++mi)
#pragma unroll
      for (int ni = 0; ni < 4; ++ni)
        acc[mi][ni] = __builtin_amdgcn_mfma_f32_16x16x32_bf16(
            pA[mi], pB[ni], acc[mi][ni], 0, 0, 0);
    __builtin_amdgcn_s_setprio(0);

    // prefetch tile t+1 A(mi0-3) (pA dead after half1)
    if (rd) {
#pragma unroll
      for (int mi = 0; mi < 4; ++mi)
        pA[mi] = *(const bf16x8*)&As[nslot + (aRow + mi * 16) * 32 + csw];
    }

    // half2 MFMA (qA x pB)
    __builtin_amdgcn_s_setprio(1);
#pragma unroll
    for (int mi = 0; mi < 4; ++mi)
#pragma unroll
      for (int ni = 0; ni < 4; ++ni)
        acc[4 + mi][ni] = __builtin_amdgcn_mfma_f32_16x16x32_bf16(
            qA[mi], pB[ni], acc[4 + mi][ni], 0, 0, 0);
    __builtin_amdgcn_s_setprio(0);

    // prefetch tile t+1 B (pB dead after half2)
    if (rd) {
#pragma unroll
      for (int ni = 0; ni < 4; ++ni)
        pB[ni] = *(const bf16x8*)&Bs[nslot + (bRow + ni * 16) * 32 + csw];
    }

    // stage tile t+3 -> slot (t+3)&3
    if (pf) {
      gload_lds16(A + aoff[0] + kof, As + wslot + ldso[0]);
      gload_lds16(B + boff[0] + kof, Bs + wslot + ldso[0]);
      gload_lds16(A + aoff[1] + kof, As + wslot + ldso[1]);
      gload_lds16(B + boff[1] + kof, Bs + wslot + ldso[1]);
      VM4();  // everything older than own 4 newest landed => tile t+2 ready
    } else {
      VM0();  // tail: drain remaining stage loads
    }
    SBAR();
  }

  // ---- epilogue: C/D layout col=lane&15, row=(lane>>4)*4+reg ----
#pragma unroll
  for (int ni = 0; ni < 4; ++ni) {
    const int col = bn0 + wn * 64 + ni * 16 + lr;
    const float bv = bias[col];
#pragma unroll
    for (int mi = 0; mi < 8; ++mi) {
      const int row0 = bm0 + wm * 128 + mi * 16 + g * 4;
#pragma unroll
      for (int j = 0; j < 4; ++j)
        y[(size_t)(row0 + j) * n + col] = acc[mi][ni][j] + bv;
    }
  }
}

// ---------------- fallback (no ws needed) ----------------

#define LDP 72

__global__ __launch_bounds__(256) void circ_gemm_fb(
    const float* __restrict__ x, const float* __restrict__ r,
    const float* __restrict__ bias, float* __restrict__ y, int n) {
  __shared__ unsigned short Asf[128][LDP];
  __shared__ unsigned short Bsf[128][LDP];

  const int tid = threadIdx.x;
  const int wid = tid >> 6;
  const int lane = tid & 63;
  const int bm0 = blockIdx.y * 128;
  const int bn0 = blockIdx.x * 128;
  const int m0w = (wid >> 1) * 64;
  const int n0w = (wid & 1) * 64;
  const int lr = lane & 15;
  const int lk = (lane >> 4) * 8;
  const int mask = n - 1;

  f32x4 acc[4][4];
#pragma unroll
  for (int i = 0; i < 4; ++i)
#pragma unroll
    for (int j = 0; j < 4; ++j) acc[i][j] = (f32x4){0.f, 0.f, 0.f, 0.f};

  const int arow = tid >> 4;
  const int acol = (tid & 15) * 4;
  const int bnn = tid >> 1;
  const int bk0 = (tid & 1) * 32;

  for (int k0 = 0; k0 < n; k0 += 64) {
#pragma unroll
    for (int p = 0; p < 8; ++p) {
      const float4 v =
          *(const float4*)&x[(size_t)(bm0 + arow + p * 16) * n + k0 + acol];
      us4 hh;
      hh.x = f2bf(v.x); hh.y = f2bf(v.y); hh.z = f2bf(v.z); hh.w = f2bf(v.w);
      *(us4*)&Asf[arow + p * 16][acol] = hh;
    }
    {
      const int base = k0 + bk0 - bn0 - bnn;
#pragma unroll
      for (int kq = 0; kq < 32; kq += 4) {
        us4 hh;
        hh.x = f2bf(r[(base + kq + 0) & mask]);
        hh.y = f2bf(r[(base + kq + 1) & mask]);
        hh.z = f2bf(r[(base + kq + 2) & mask]);
        hh.w = f2bf(r[(base + kq + 3) & mask]);
        *(us4*)&Bsf[bnn][bk0 + kq] = hh;
      }
    }
    __syncthreads();

#pragma unroll
    for (int kk = 0; kk < 2; ++kk) {
      bf16x8 af[4], bfr[4];
#pragma unroll
      for (int mi = 0; mi < 4; ++mi)
        af[mi] = *(const bf16x8*)&Asf[m0w + mi * 16 + lr][kk * 32 + lk];
#pragma unroll
      for (int ni = 0; ni < 4; ++ni)
        bfr[ni] = *(const bf16x8*)&Bsf[n0w + ni * 16 + lr][kk * 32 + lk];
#pragma unroll
      for (int mi = 0; mi < 4; ++mi)
#pragma unroll
        for (int ni = 0; ni < 4; ++ni)
          acc[mi][ni] = __builtin_amdgcn_mfma_f32_16x16x32_bf16(
              af[mi], bfr[ni], acc[mi][ni], 0, 0, 0);
    }
    __syncthreads();
  }

#pragma unroll
  for (int ni = 0; ni < 4; ++ni) {
    const int col = bn0 + n0w + ni * 16 + lr;
    const float bv = bias[col];
#pragma unroll
    for (int mi = 0; mi < 4; ++mi) {
      const int row0 = bm0 + m0w + mi * 16 + (lane >> 4) * 4;
#pragma unroll
      for (int j = 0; j < 4; ++j)
        y[(size_t)(row0 + j) * n + col] = acc[mi][ni][j] + bv;
    }
  }
}

// ---------------- launch ----------------

extern "C" void kernel_launch(void* const* d_in, const int* in_sizes, int n_in,
                              void* d_out, int out_size, void* d_ws,
                              size_t ws_size, hipStream_t stream) {
  const float* x = (const float*)d_in[0];
  const float* r = (const float*)d_in[1];
  const float* b = (const float*)d_in[2];
  float* y = (float*)d_out;
  const int n = in_sizes[1];          // 4096
  const int batch = in_sizes[0] / n;  // 8192

  const size_t xb_elems = (size_t)batch * n;
  const size_t bt_elems = (size_t)n * n;
  const size_t need = (xb_elems + bt_elems) * sizeof(unsigned short);

  if (ws_size >= need && (n % 256) == 0 && (batch % 256) == 0 && n >= 256) {
    unsigned short* xb = (unsigned short*)d_ws;
    unsigned short* bt = xb + xb_elems;
    int logn = 31 - __builtin_clz((unsigned)n);
    conv_x_kernel<<<2048, 256, 0, stream>>>(x, xb, xb_elems / 8);
    build_bt_kernel<<<1024, 256, 0, stream>>>(r, bt, n, logn);
    dim3 grid((batch / 256) * (n / 256));
    circ_gemm6<<<grid, 512, 0, stream>>>(xb, bt, b, y, n, n / 256);
  } else {
    dim3 grid(n / 128, batch / 128);
    circ_gemm_fb<<<grid, 256, 0, stream>>>(x, r, b, y, n);
  }
}

// Round 7
// 207.747 us; speedup vs baseline: 1.5426x; 1.5426x over previous
//
#include <hip/hip_runtime.h>
#include <hip/hip_bf16.h>
#include <math.h>

// y[b,i] = sum_j x[b,j] * r[(j-i) mod N] + bias[i]
//        = circular conv: y = IFFT(FFT(x) * FFT(c)) + bias, c[k] = r[(-k) mod N]
// FFT route (N=4096): radix-8, 4 stages, fp32, in-LDS.
//   forward = DIF (natural in -> digit-reversed out)
//   pointwise multiply in digit-reversed order (C precomputed in SAME order)
//   inverse = DIT (digit-reversed in -> natural out), exact stage-wise inverse.
// LDS: data[4352] + twiddle[4352] float2 (pad16: p(i)=i+(i>>4)) = 69.6 KB -> 2 blocks/CU.

#define NFFT 4096
#define PAD(i) ((i) + ((i) >> 4))

typedef __attribute__((ext_vector_type(4))) float f32x4;
typedef __attribute__((ext_vector_type(4))) unsigned short us4;

__device__ __forceinline__ float2 cadd(float2 a, float2 b) {
  return make_float2(a.x + b.x, a.y + b.y);
}
__device__ __forceinline__ float2 csub(float2 a, float2 b) {
  return make_float2(a.x - b.x, a.y - b.y);
}
__device__ __forceinline__ float2 cmul(float2 a, float2 b) {
  return make_float2(a.x * b.x - a.y * b.y, a.x * b.y + a.y * b.x);
}
__device__ __forceinline__ float2 cmulj(float2 a, float2 b) {  // a * conj(b)
  return make_float2(a.x * b.x + a.y * b.y, a.y * b.x - a.x * b.y);
}
__device__ __forceinline__ float2 mni(float2 a) {  // a * (-i)
  return make_float2(a.y, -a.x);
}
__device__ __forceinline__ float2 mpi(float2 a) {  // a * (+i)
  return make_float2(-a.y, a.x);
}

// ---- forward DIF radix-8 stage, span M, twiddle step = NFFT/(8M) ----
// butterfly u: n=u&(M-1), base=(u>>log2M)*8M+n; out[base+qM] = (sum_p a_p w8^{pq}) * W^{nq}
template <int M>
__device__ __forceinline__ void fwd_stage(float2* d, const float2* tw, int tid) {
  constexpr int STEP = NFFT / (8 * M);
#pragma unroll
  for (int v = 0; v < 2; ++v) {
    const int u = tid + 256 * v;
    const int n = u & (M - 1);
    const int base = ((u & ~(M - 1)) << 3) + n;
    float2 a[8];
#pragma unroll
    for (int q = 0; q < 8; ++q) a[q] = d[PAD(base + q * M)];
    // fft8: X_k = sum_p a_p e^{-2pi i pk/8}
    float2 es0 = cadd(a[0], a[4]), ed0 = csub(a[0], a[4]);
    float2 es1 = cadd(a[2], a[6]), ed1 = csub(a[2], a[6]);
    float2 E0 = cadd(es0, es1), E2 = csub(es0, es1);
    float2 E1 = cadd(ed0, mni(ed1)), E3 = cadd(ed0, mpi(ed1));
    float2 os0 = cadd(a[1], a[5]), od0 = csub(a[1], a[5]);
    float2 os1 = cadd(a[3], a[7]), od1 = csub(a[3], a[7]);
    float2 O0 = cadd(os0, os1), O2 = csub(os0, os1);
    float2 O1 = cadd(od0, mni(od1)), O3 = cadd(od0, mpi(od1));
    const float c = 0.70710678118654752f;
    O1 = make_float2(c * (O1.x + O1.y), c * (O1.y - O1.x));  // * c(1-i)
    O2 = mni(O2);                                            // * -i
    O3 = make_float2(c * (O3.y - O3.x), -c * (O3.x + O3.y)); // * c(-1-i)
    float2 X[8];
    X[0] = cadd(E0, O0); X[4] = csub(E0, O0);
    X[1] = cadd(E1, O1); X[5] = csub(E1, O1);
    X[2] = cadd(E2, O2); X[6] = csub(E2, O2);
    X[3] = cadd(E3, O3); X[7] = csub(E3, O3);
    d[PAD(base)] = X[0];
    if constexpr (M == 1) {
#pragma unroll
      for (int q = 1; q < 8; ++q) d[PAD(base + q * M)] = X[q];  // n=0: W=1
    } else {
#pragma unroll
      for (int q = 1; q < 8; ++q)
        d[PAD(base + q * M)] = cmul(X[q], tw[PAD(n * STEP * q)]);
    }
  }
}

// ---- inverse DIT radix-8 stage (exact inverse of fwd_stage<M>, unscaled) ----
template <int M>
__device__ __forceinline__ void inv_stage(float2* d, const float2* tw, int tid) {
  constexpr int STEP = NFFT / (8 * M);
#pragma unroll
  for (int v = 0; v < 2; ++v) {
    const int u = tid + 256 * v;
    const int n = u & (M - 1);
    const int base = ((u & ~(M - 1)) << 3) + n;
    float2 z[8];
    z[0] = d[PAD(base)];
    if constexpr (M == 1) {
#pragma unroll
      for (int q = 1; q < 8; ++q) z[q] = d[PAD(base + q * M)];
    } else {
#pragma unroll
      for (int q = 1; q < 8; ++q)
        z[q] = cmulj(d[PAD(base + q * M)], tw[PAD(n * STEP * q)]);
    }
    // ifft8: X_p = sum_q z_q e^{+2pi i pq/8}
    float2 es0 = cadd(z[0], z[4]), ed0 = csub(z[0], z[4]);
    float2 es1 = cadd(z[2], z[6]), ed1 = csub(z[2], z[6]);
    float2 E0 = cadd(es0, es1), E2 = csub(es0, es1);
    float2 E1 = cadd(ed0, mpi(ed1)), E3 = cadd(ed0, mni(ed1));
    float2 os0 = cadd(z[1], z[5]), od0 = csub(z[1], z[5]);
    float2 os1 = cadd(z[3], z[7]), od1 = csub(z[3], z[7]);
    float2 O0 = cadd(os0, os1), O2 = csub(os0, os1);
    float2 O1 = cadd(od0, mpi(od1)), O3 = cadd(od0, mni(od1));
    const float c = 0.70710678118654752f;
    O1 = make_float2(c * (O1.x - O1.y), c * (O1.x + O1.y));   // * c(1+i)
    O2 = mpi(O2);                                             // * +i
    O3 = make_float2(-c * (O3.x + O3.y), c * (O3.x - O3.y));  // * c(-1+i)
    float2 X[8];
    X[0] = cadd(E0, O0); X[4] = csub(E0, O0);
    X[1] = cadd(E1, O1); X[5] = csub(E1, O1);
    X[2] = cadd(E2, O2); X[6] = csub(E2, O2);
    X[3] = cadd(E3, O3); X[7] = csub(E3, O3);
#pragma unroll
    for (int p = 0; p < 8; ++p) d[PAD(base + p * M)] = X[p];
  }
}

// ---------------- kernel 0: twiddle table tw[j] = e^{-2pi i j/N} ----------------
__global__ __launch_bounds__(256) void build_tw(float2* __restrict__ twg) {
  const int j = blockIdx.x * 256 + threadIdx.x;
  if (j < NFFT) {
    double ang = (-2.0 * 3.14159265358979323846) * (double)j / (double)NFFT;
    twg[j] = make_float2((float)cos(ang), (float)sin(ang));
  }
}

// ---------------- kernel 1: C = FFT(c), digit-reversed order ----------------
__global__ __launch_bounds__(256) void build_C(const float* __restrict__ r,
                                               const float2* __restrict__ twg,
                                               float2* __restrict__ Cg) {
  __shared__ float2 d[PAD(NFFT - 1) + 1 + 8];
  __shared__ float2 tws[PAD(NFFT - 1) + 1 + 8];
  const int tid = threadIdx.x;
  for (int i = tid; i < NFFT; i += 256) {
    tws[PAD(i)] = twg[i];
    d[PAD(i)] = make_float2(r[(NFFT - i) & (NFFT - 1)], 0.f);
  }
  __syncthreads();
  fwd_stage<512>(d, tws, tid); __syncthreads();
  fwd_stage<64>(d, tws, tid);  __syncthreads();
  fwd_stage<8>(d, tws, tid);   __syncthreads();
  fwd_stage<1>(d, tws, tid);   __syncthreads();
  for (int i = tid; i < NFFT; i += 256) Cg[i] = d[PAD(i)];
}

// ---------------- kernel 2: per-row FFT convolution ----------------
__global__ __launch_bounds__(256) void fft_conv(const float* __restrict__ x,
                                                const float2* __restrict__ Cg,
                                                const float2* __restrict__ twg,
                                                const float* __restrict__ bias,
                                                float* __restrict__ y) {
  __shared__ float2 d[PAD(NFFT - 1) + 1 + 8];
  __shared__ float2 tws[PAD(NFFT - 1) + 1 + 8];
  const int tid = threadIdx.x;
  const size_t row = blockIdx.x;
  const float4* x4 = (const float4*)(x + row * NFFT);
  const float4* b4 = (const float4*)bias;
  float4* y4 = (float4*)(y + row * NFFT);

  // copy twiddles + load row (real -> complex)
  for (int i = tid; i < NFFT; i += 256) tws[PAD(i)] = twg[i];
#pragma unroll
  for (int w = 0; w < 4; ++w) {
    const int i4 = tid + 256 * w;
    const float4 v = x4[i4];
    const int i0 = i4 * 4;
    d[PAD(i0 + 0)] = make_float2(v.x, 0.f);
    d[PAD(i0 + 1)] = make_float2(v.y, 0.f);
    d[PAD(i0 + 2)] = make_float2(v.z, 0.f);
    d[PAD(i0 + 3)] = make_float2(v.w, 0.f);
  }
  __syncthreads();

  // forward DIF
  fwd_stage<512>(d, tws, tid); __syncthreads();
  fwd_stage<64>(d, tws, tid);  __syncthreads();
  fwd_stage<8>(d, tws, tid);   __syncthreads();
  fwd_stage<1>(d, tws, tid);   __syncthreads();

  // pointwise multiply by C (both in identical digit-reversed order)
  for (int i = tid; i < NFFT; i += 256) d[PAD(i)] = cmul(d[PAD(i)], Cg[i]);
  __syncthreads();

  // inverse DIT (reverse stage order, conj twiddles), unscaled (x4096)
  inv_stage<1>(d, tws, tid);   __syncthreads();
  inv_stage<8>(d, tws, tid);   __syncthreads();
  inv_stage<64>(d, tws, tid);  __syncthreads();
  inv_stage<512>(d, tws, tid); __syncthreads();

  // store real part * 1/N + bias
  const float s = 1.0f / (float)NFFT;
#pragma unroll
  for (int w = 0; w < 4; ++w) {
    const int i4 = tid + 256 * w;
    const int i0 = i4 * 4;
    const float4 bv = b4[i4];
    float4 o;
    o.x = d[PAD(i0 + 0)].x * s + bv.x;
    o.y = d[PAD(i0 + 1)].x * s + bv.y;
    o.z = d[PAD(i0 + 2)].x * s + bv.z;
    o.w = d[PAD(i0 + 3)].x * s + bv.w;
    y4[i4] = o;
  }
}

// ---------------- fallback GEMM (any pow2 n % 128 == 0, no ws needed) ----------------

typedef __attribute__((ext_vector_type(8))) short bf16x8;

__device__ __forceinline__ unsigned short f2bf(float f) {
  union { __hip_bfloat16 h; unsigned short u; } v;
  v.h = __float2bfloat16(f);
  return v.u;
}

#define LDP 72

__global__ __launch_bounds__(256) void circ_gemm_fb(
    const float* __restrict__ x, const float* __restrict__ r,
    const float* __restrict__ bias, float* __restrict__ y, int n) {
  __shared__ unsigned short Asf[128][LDP];
  __shared__ unsigned short Bsf[128][LDP];

  const int tid = threadIdx.x;
  const int wid = tid >> 6;
  const int lane = tid & 63;
  const int bm0 = blockIdx.y * 128;
  const int bn0 = blockIdx.x * 128;
  const int m0w = (wid >> 1) * 64;
  const int n0w = (wid & 1) * 64;
  const int lr = lane & 15;
  const int lk = (lane >> 4) * 8;
  const int mask = n - 1;

  f32x4 acc[4][4];
#pragma unroll
  for (int i = 0; i < 4; ++i)
#pragma unroll
    for (int j = 0; j < 4; ++j) acc[i][j] = (f32x4){0.f, 0.f, 0.f, 0.f};

  const int arow = tid >> 4;
  const int acol = (tid & 15) * 4;
  const int bnn = tid >> 1;
  const int bk0 = (tid & 1) * 32;

  for (int k0 = 0; k0 < n; k0 += 64) {
#pragma unroll
    for (int p = 0; p < 8; ++p) {
      const float4 v =
          *(const float4*)&x[(size_t)(bm0 + arow + p * 16) * n + k0 + acol];
      us4 hh;
      hh.x = f2bf(v.x); hh.y = f2bf(v.y); hh.z = f2bf(v.z); hh.w = f2bf(v.w);
      *(us4*)&Asf[arow + p * 16][acol] = hh;
    }
    {
      const int base = k0 + bk0 - bn0 - bnn;
#pragma unroll
      for (int kq = 0; kq < 32; kq += 4) {
        us4 hh;
        hh.x = f2bf(r[(base + kq + 0) & mask]);
        hh.y = f2bf(r[(base + kq + 1) & mask]);
        hh.z = f2bf(r[(base + kq + 2) & mask]);
        hh.w = f2bf(r[(base + kq + 3) & mask]);
        *(us4*)&Bsf[bnn][bk0 + kq] = hh;
      }
    }
    __syncthreads();

#pragma unroll
    for (int kk = 0; kk < 2; ++kk) {
      bf16x8 af[4], bfr[4];
#pragma unroll
      for (int mi = 0; mi < 4; ++mi)
        af[mi] = *(const bf16x8*)&Asf[m0w + mi * 16 + lr][kk * 32 + lk];
#pragma unroll
      for (int ni = 0; ni < 4; ++ni)
        bfr[ni] = *(const bf16x8*)&Bsf[n0w + ni * 16 + lr][kk * 32 + lk];
#pragma unroll
      for (int mi = 0; mi < 4; ++mi)
#pragma unroll
        for (int ni = 0; ni < 4; ++ni)
          acc[mi][ni] = __builtin_amdgcn_mfma_f32_16x16x32_bf16(
              af[mi], bfr[ni], acc[mi][ni], 0, 0, 0);
    }
    __syncthreads();
  }

#pragma unroll
  for (int ni = 0; ni < 4; ++ni) {
    const int col = bn0 + n0w + ni * 16 + lr;
    const float bv = bias[col];
#pragma unroll
    for (int mi = 0; mi < 4; ++mi) {
      const int row0 = bm0 + m0w + mi * 16 + (lane >> 4) * 4;
#pragma unroll
      for (int j = 0; j < 4; ++j)
        y[(size_t)(row0 + j) * n + col] = acc[mi][ni][j] + bv;
    }
  }
}

// ---------------- launch ----------------

extern "C" void kernel_launch(void* const* d_in, const int* in_sizes, int n_in,
                              void* d_out, int out_size, void* d_ws,
                              size_t ws_size, hipStream_t stream) {
  const float* x = (const float*)d_in[0];
  const float* r = (const float*)d_in[1];
  const float* b = (const float*)d_in[2];
  float* y = (float*)d_out;
  const int n = in_sizes[1];          // 4096
  const int batch = in_sizes[0] / n;  // 8192

  if (n == NFFT && ws_size >= 2 * NFFT * sizeof(float2)) {
    float2* twg = (float2*)d_ws;
    float2* Cg = twg + NFFT;
    build_tw<<<NFFT / 256, 256, 0, stream>>>(twg);
    build_C<<<1, 256, 0, stream>>>(r, twg, Cg);
    fft_conv<<<batch, 256, 0, stream>>>(x, Cg, twg, b, y);
  } else {
    dim3 grid(n / 128, batch / 128);
    circ_gemm_fb<<<grid, 256, 0, stream>>>(x, r, b, y, n);
  }
}

// Round 8
// 158.712 us; speedup vs baseline: 2.0193x; 1.3090x over previous
//
#include <hip/hip_runtime.h>
#include <hip/hip_bf16.h>
#include <math.h>

// y[b,i] = sum_j x[b,j] * r[(j-i) mod N] + bias[i]
//        = circular conv: y = IFFT(FFT(x) * FFT(c)) + bias, c[k] = r[(-k) mod N]
// FFT route (N=4096): radix-8, 4 stages, fp32, in-LDS.
//   - TWO rows packed per FFT: z = x1 + i*x2 -> y1 = Re, y2 = Im (conv of
//     real data is real; exact by linearity).
//   - twiddles read from global (L1-cached), NOT staged in LDS ->
//     LDS = 34.9 KB -> 4 blocks/CU.

#define NFFT 4096
#define PAD(i) ((i) + ((i) >> 4))

typedef __attribute__((ext_vector_type(4))) float f32x4;
typedef __attribute__((ext_vector_type(4))) unsigned short us4;

__device__ __forceinline__ float2 cadd(float2 a, float2 b) {
  return make_float2(a.x + b.x, a.y + b.y);
}
__device__ __forceinline__ float2 csub(float2 a, float2 b) {
  return make_float2(a.x - b.x, a.y - b.y);
}
__device__ __forceinline__ float2 cmul(float2 a, float2 b) {
  return make_float2(a.x * b.x - a.y * b.y, a.x * b.y + a.y * b.x);
}
__device__ __forceinline__ float2 cmulj(float2 a, float2 b) {  // a * conj(b)
  return make_float2(a.x * b.x + a.y * b.y, a.y * b.x - a.x * b.y);
}
__device__ __forceinline__ float2 mni(float2 a) {  // a * (-i)
  return make_float2(a.y, -a.x);
}
__device__ __forceinline__ float2 mpi(float2 a) {  // a * (+i)
  return make_float2(-a.y, a.x);
}

// ---- forward DIF radix-8 stage, span M, twiddle step = NFFT/(8M) ----
template <int M>
__device__ __forceinline__ void fwd_stage(float2* d, const float2* __restrict__ tw,
                                          int tid) {
  constexpr int STEP = NFFT / (8 * M);
#pragma unroll
  for (int v = 0; v < 2; ++v) {
    const int u = tid + 256 * v;
    const int n = u & (M - 1);
    const int base = ((u & ~(M - 1)) << 3) + n;
    float2 a[8];
#pragma unroll
    for (int q = 0; q < 8; ++q) a[q] = d[PAD(base + q * M)];
    // fft8: X_k = sum_p a_p e^{-2pi i pk/8}
    float2 es0 = cadd(a[0], a[4]), ed0 = csub(a[0], a[4]);
    float2 es1 = cadd(a[2], a[6]), ed1 = csub(a[2], a[6]);
    float2 E0 = cadd(es0, es1), E2 = csub(es0, es1);
    float2 E1 = cadd(ed0, mni(ed1)), E3 = cadd(ed0, mpi(ed1));
    float2 os0 = cadd(a[1], a[5]), od0 = csub(a[1], a[5]);
    float2 os1 = cadd(a[3], a[7]), od1 = csub(a[3], a[7]);
    float2 O0 = cadd(os0, os1), O2 = csub(os0, os1);
    float2 O1 = cadd(od0, mni(od1)), O3 = cadd(od0, mpi(od1));
    const float c = 0.70710678118654752f;
    O1 = make_float2(c * (O1.x + O1.y), c * (O1.y - O1.x));  // * c(1-i)
    O2 = mni(O2);                                            // * -i
    O3 = make_float2(c * (O3.y - O3.x), -c * (O3.x + O3.y)); // * c(-1-i)
    float2 X[8];
    X[0] = cadd(E0, O0); X[4] = csub(E0, O0);
    X[1] = cadd(E1, O1); X[5] = csub(E1, O1);
    X[2] = cadd(E2, O2); X[6] = csub(E2, O2);
    X[3] = cadd(E3, O3); X[7] = csub(E3, O3);
    d[PAD(base)] = X[0];
    if constexpr (M == 1) {
#pragma unroll
      for (int q = 1; q < 8; ++q) d[PAD(base + q * M)] = X[q];  // n=0: W=1
    } else {
#pragma unroll
      for (int q = 1; q < 8; ++q)
        d[PAD(base + q * M)] = cmul(X[q], tw[n * STEP * q]);
    }
  }
}

// ---- inverse DIT radix-8 stage (exact inverse of fwd_stage<M>, unscaled) ----
template <int M>
__device__ __forceinline__ void inv_stage(float2* d, const float2* __restrict__ tw,
                                          int tid) {
  constexpr int STEP = NFFT / (8 * M);
#pragma unroll
  for (int v = 0; v < 2; ++v) {
    const int u = tid + 256 * v;
    const int n = u & (M - 1);
    const int base = ((u & ~(M - 1)) << 3) + n;
    float2 z[8];
    z[0] = d[PAD(base)];
    if constexpr (M == 1) {
#pragma unroll
      for (int q = 1; q < 8; ++q) z[q] = d[PAD(base + q * M)];
    } else {
#pragma unroll
      for (int q = 1; q < 8; ++q)
        z[q] = cmulj(d[PAD(base + q * M)], tw[n * STEP * q]);
    }
    // ifft8: X_p = sum_q z_q e^{+2pi i pq/8}
    float2 es0 = cadd(z[0], z[4]), ed0 = csub(z[0], z[4]);
    float2 es1 = cadd(z[2], z[6]), ed1 = csub(z[2], z[6]);
    float2 E0 = cadd(es0, es1), E2 = csub(es0, es1);
    float2 E1 = cadd(ed0, mpi(ed1)), E3 = cadd(ed0, mni(ed1));
    float2 os0 = cadd(z[1], z[5]), od0 = csub(z[1], z[5]);
    float2 os1 = cadd(z[3], z[7]), od1 = csub(z[3], z[7]);
    float2 O0 = cadd(os0, os1), O2 = csub(os0, os1);
    float2 O1 = cadd(od0, mpi(od1)), O3 = cadd(od0, mni(od1));
    const float c = 0.70710678118654752f;
    O1 = make_float2(c * (O1.x - O1.y), c * (O1.x + O1.y));   // * c(1+i)
    O2 = mpi(O2);                                             // * +i
    O3 = make_float2(-c * (O3.x + O3.y), c * (O3.x - O3.y));  // * c(-1+i)
    float2 X[8];
    X[0] = cadd(E0, O0); X[4] = csub(E0, O0);
    X[1] = cadd(E1, O1); X[5] = csub(E1, O1);
    X[2] = cadd(E2, O2); X[6] = csub(E2, O2);
    X[3] = cadd(E3, O3); X[7] = csub(E3, O3);
#pragma unroll
    for (int p = 0; p < 8; ++p) d[PAD(base + p * M)] = X[p];
  }
}

// ---------------- kernel 0: twiddle table tw[j] = e^{-2pi i j/N} ----------------
__global__ __launch_bounds__(256) void build_tw(float2* __restrict__ twg) {
  const int j = blockIdx.x * 256 + threadIdx.x;
  if (j < NFFT) {
    double ang = (-2.0 * 3.14159265358979323846) * (double)j / (double)NFFT;
    twg[j] = make_float2((float)cos(ang), (float)sin(ang));
  }
}

// ---------------- kernel 1: C = FFT(c), digit-reversed order ----------------
__global__ __launch_bounds__(256) void build_C(const float* __restrict__ r,
                                               const float2* __restrict__ twg,
                                               float2* __restrict__ Cg) {
  __shared__ float2 d[PAD(NFFT - 1) + 1 + 8];
  const int tid = threadIdx.x;
  for (int i = tid; i < NFFT; i += 256)
    d[PAD(i)] = make_float2(r[(NFFT - i) & (NFFT - 1)], 0.f);
  __syncthreads();
  fwd_stage<512>(d, twg, tid); __syncthreads();
  fwd_stage<64>(d, twg, tid);  __syncthreads();
  fwd_stage<8>(d, twg, tid);   __syncthreads();
  fwd_stage<1>(d, twg, tid);   __syncthreads();
  for (int i = tid; i < NFFT; i += 256) Cg[i] = d[PAD(i)];
}

// ---------------- kernel 2: packed 2-row FFT convolution ----------------
// z = x_row0 + i * x_row1; y = IFFT(FFT(z) .* C); y_row0 = Re, y_row1 = Im.
__global__ __launch_bounds__(256, 4) void fft_conv2(
    const float* __restrict__ x, const float2* __restrict__ Cg,
    const float2* __restrict__ twg, const float* __restrict__ bias,
    float* __restrict__ y) {
  __shared__ float2 d[PAD(NFFT - 1) + 1 + 8];
  const int tid = threadIdx.x;
  const size_t r0 = 2 * (size_t)blockIdx.x;
  const float4* x0 = (const float4*)(x + r0 * NFFT);
  const float4* x1 = (const float4*)(x + (r0 + 1) * NFFT);
  const float4* b4 = (const float4*)bias;
  float4* y0 = (float4*)(y + r0 * NFFT);
  float4* y1 = (float4*)(y + (r0 + 1) * NFFT);

  // load both rows packed: d[i] = (x0[i], x1[i])
#pragma unroll
  for (int w = 0; w < 4; ++w) {
    const int i4 = tid + 256 * w;
    const float4 v0 = x0[i4];
    const float4 v1 = x1[i4];
    const int i0 = i4 * 4;
    d[PAD(i0 + 0)] = make_float2(v0.x, v1.x);
    d[PAD(i0 + 1)] = make_float2(v0.y, v1.y);
    d[PAD(i0 + 2)] = make_float2(v0.z, v1.z);
    d[PAD(i0 + 3)] = make_float2(v0.w, v1.w);
  }
  __syncthreads();

  // forward DIF
  fwd_stage<512>(d, twg, tid); __syncthreads();
  fwd_stage<64>(d, twg, tid);  __syncthreads();
  fwd_stage<8>(d, twg, tid);   __syncthreads();
  fwd_stage<1>(d, twg, tid);   __syncthreads();

  // pointwise multiply by C (both in identical digit-reversed order)
  for (int i = tid; i < NFFT; i += 256) d[PAD(i)] = cmul(d[PAD(i)], Cg[i]);
  __syncthreads();

  // inverse DIT (reverse stage order, conj twiddles), unscaled (x4096)
  inv_stage<1>(d, twg, tid);   __syncthreads();
  inv_stage<8>(d, twg, tid);   __syncthreads();
  inv_stage<64>(d, twg, tid);  __syncthreads();
  inv_stage<512>(d, twg, tid); __syncthreads();

  // store: row0 = Re/N + bias, row1 = Im/N + bias
  const float s = 1.0f / (float)NFFT;
#pragma unroll
  for (int w = 0; w < 4; ++w) {
    const int i4 = tid + 256 * w;
    const int i0 = i4 * 4;
    const float4 bv = b4[i4];
    const float2 d0 = d[PAD(i0 + 0)];
    const float2 d1 = d[PAD(i0 + 1)];
    const float2 d2 = d[PAD(i0 + 2)];
    const float2 d3 = d[PAD(i0 + 3)];
    float4 o0, o1;
    o0.x = d0.x * s + bv.x; o1.x = d0.y * s + bv.x;
    o0.y = d1.x * s + bv.y; o1.y = d1.y * s + bv.y;
    o0.z = d2.x * s + bv.z; o1.z = d2.y * s + bv.z;
    o0.w = d3.x * s + bv.w; o1.w = d3.y * s + bv.w;
    y0[i4] = o0;
    y1[i4] = o1;
  }
}

// ---------------- fallback GEMM (no ws / odd shapes) ----------------

typedef __attribute__((ext_vector_type(8))) short bf16x8;

__device__ __forceinline__ unsigned short f2bf(float f) {
  union { __hip_bfloat16 h; unsigned short u; } v;
  v.h = __float2bfloat16(f);
  return v.u;
}

#define LDP 72

__global__ __launch_bounds__(256) void circ_gemm_fb(
    const float* __restrict__ x, const float* __restrict__ r,
    const float* __restrict__ bias, float* __restrict__ y, int n) {
  __shared__ unsigned short Asf[128][LDP];
  __shared__ unsigned short Bsf[128][LDP];

  const int tid = threadIdx.x;
  const int wid = tid >> 6;
  const int lane = tid & 63;
  const int bm0 = blockIdx.y * 128;
  const int bn0 = blockIdx.x * 128;
  const int m0w = (wid >> 1) * 64;
  const int n0w = (wid & 1) * 64;
  const int lr = lane & 15;
  const int lk = (lane >> 4) * 8;
  const int mask = n - 1;

  f32x4 acc[4][4];
#pragma unroll
  for (int i = 0; i < 4; ++i)
#pragma unroll
    for (int j = 0; j < 4; ++j) acc[i][j] = (f32x4){0.f, 0.f, 0.f, 0.f};

  const int arow = tid >> 4;
  const int acol = (tid & 15) * 4;
  const int bnn = tid >> 1;
  const int bk0 = (tid & 1) * 32;

  for (int k0 = 0; k0 < n; k0 += 64) {
#pragma unroll
    for (int p = 0; p < 8; ++p) {
      const float4 v =
          *(const float4*)&x[(size_t)(bm0 + arow + p * 16) * n + k0 + acol];
      us4 hh;
      hh.x = f2bf(v.x); hh.y = f2bf(v.y); hh.z = f2bf(v.z); hh.w = f2bf(v.w);
      *(us4*)&Asf[arow + p * 16][acol] = hh;
    }
    {
      const int base = k0 + bk0 - bn0 - bnn;
#pragma unroll
      for (int kq = 0; kq < 32; kq += 4) {
        us4 hh;
        hh.x = f2bf(r[(base + kq + 0) & mask]);
        hh.y = f2bf(r[(base + kq + 1) & mask]);
        hh.z = f2bf(r[(base + kq + 2) & mask]);
        hh.w = f2bf(r[(base + kq + 3) & mask]);
        *(us4*)&Bsf[bnn][bk0 + kq] = hh;
      }
    }
    __syncthreads();

#pragma unroll
    for (int kk = 0; kk < 2; ++kk) {
      bf16x8 af[4], bfr[4];
#pragma unroll
      for (int mi = 0; mi < 4; ++mi)
        af[mi] = *(const bf16x8*)&Asf[m0w + mi * 16 + lr][kk * 32 + lk];
#pragma unroll
      for (int ni = 0; ni < 4; ++ni)
        bfr[ni] = *(const bf16x8*)&Bsf[n0w + ni * 16 + lr][kk * 32 + lk];
#pragma unroll
      for (int mi = 0; mi < 4; ++mi)
#pragma unroll
        for (int ni = 0; ni < 4; ++ni)
          acc[mi][ni] = __builtin_amdgcn_mfma_f32_16x16x32_bf16(
              af[mi], bfr[ni], acc[mi][ni], 0, 0, 0);
    }
    __syncthreads();
  }

#pragma unroll
  for (int ni = 0; ni < 4; ++ni) {
    const int col = bn0 + n0w + ni * 16 + lr;
    const float bv = bias[col];
#pragma unroll
    for (int mi = 0; mi < 4; ++mi) {
      const int row0 = bm0 + m0w + mi * 16 + (lane >> 4) * 4;
#pragma unroll
      for (int j = 0; j < 4; ++j)
        y[(size_t)(row0 + j) * n + col] = acc[mi][ni][j] + bv;
    }
  }
}

// ---------------- launch ----------------

extern "C" void kernel_launch(void* const* d_in, const int* in_sizes, int n_in,
                              void* d_out, int out_size, void* d_ws,
                              size_t ws_size, hipStream_t stream) {
  const float* x = (const float*)d_in[0];
  const float* r = (const float*)d_in[1];
  const float* b = (const float*)d_in[2];
  float* y = (float*)d_out;
  const int n = in_sizes[1];          // 4096
  const int batch = in_sizes[0] / n;  // 8192

  if (n == NFFT && (batch & 1) == 0 && ws_size >= 2 * NFFT * sizeof(float2)) {
    float2* twg = (float2*)d_ws;
    float2* Cg = twg + NFFT;
    build_tw<<<NFFT / 256, 256, 0, stream>>>(twg);
    build_C<<<1, 256, 0, stream>>>(r, twg, Cg);
    fft_conv2<<<batch / 2, 256, 0, stream>>>(x, Cg, twg, b, y);
  } else {
    dim3 grid(n / 128, batch / 128);
    circ_gemm_fb<<<grid, 256, 0, stream>>>(x, r, b, y, n);
  }
}